// Round 1
// baseline (411.621 us; speedup 1.0000x reference)
//
#include <hip/hip_runtime.h>

// BatchedSequences: scatter concatenated (T,F) fp32 rows into padded
// (B, MAX_SL, F), zero-filling tails. Pure one-pass HBM stream:
// read 203 MB + write 268 MB => ~73 us two-pass HBM floor at 6.4 TB/s.
//
// Fixed shapes (setup_inputs): B=32, F=512, MAX_SL=4096, T=99328.
//
// Measured decomposition (R0 rocprof): timed region = 2 harness poison
// fills (~167 us each, 1 GiB @ 6.4 TB/s — untouchable) + this kernel
// (~60 us). Kernel is already below the two-pass HBM floor => input S
// (203 MB < 256 MB MALL) is partially L3-resident across iterations.
//
// R1 change: loads were __builtin_nontemporal_load — on gfx950 NT marks
// lines evict-first in L2/MALL, which defeats cross-iteration residency
// of the re-read input. Use REGULAR loads for S (reuse across timed
// iterations, MALL-sized) and keep NT only on the stores (one-pass
// stream, no reuse, must not evict S).
//
// Structure: 524288 threads (2048x256) = exactly one batch's worth of
// float4s (4096 rows x 128 v4-cols), so each thread keeps ONE (p, col)
// pair and walks all 32 batches with compile-time-constant strides.
// Loads batched 4-deep ahead of stores (MLP).
//
// Note: HIP float4 is a struct — __builtin_nontemporal_* needs a native
// clang vector type, hence the ext_vector_type alias.

typedef float vf4 __attribute__((ext_vector_type(4)));

constexpr int B_N     = 32;
constexpr int FV      = 128;               // 512 floats = 128 vf4
constexpr int THREADS = 256;
constexpr int BLOCKS  = 2048;
constexpr int NTHREAD = BLOCKS * THREADS;  // 524288 = MAX_SL * FV (one batch)

__global__ __launch_bounds__(THREADS) void pad_scatter(
    const vf4* __restrict__ S,   // (T, FV)
    const int* __restrict__ L,   // (B,)
    vf4*       __restrict__ out) // (B, MAX_SL, FV)
{
    __shared__ int s_len[B_N];
    __shared__ int s_off[B_N];

    if (threadIdx.x < B_N) s_len[threadIdx.x] = L[threadIdx.x];
    __syncthreads();
    if (threadIdx.x < B_N) {
        int acc = 0;
        for (int b = 0; b < (int)threadIdx.x; ++b) acc += s_len[b];
        s_off[threadIdx.x] = acc;
    }
    __syncthreads();

    const int base = blockIdx.x * THREADS + threadIdx.x; // [0, NTHREAD)
    const int col  = base & (FV - 1);
    const int p    = base >> 7;                          // row within batch

    #pragma unroll
    for (int b0 = 0; b0 < B_N; b0 += 4) {
        vf4 v[4];
        // Issue all 4 loads before any store (branches are wave-uniform:
        // all 64 lanes of a wave share the same p).
        #pragma unroll
        for (int j = 0; j < 4; ++j) {
            const int b = b0 + j;
            v[j] = (vf4)(0.f);
            if (p < s_len[b]) {
                // Regular (cache-allocating) load: S fits in the 256 MiB
                // Infinity Cache and is re-read every iteration.
                v[j] = S[(size_t)(s_off[b] + p) * FV + col];
            }
        }
        #pragma unroll
        for (int j = 0; j < 4; ++j) {
            __builtin_nontemporal_store(
                v[j], &out[(size_t)(b0 + j) * NTHREAD + base]);
        }
    }
}

extern "C" void kernel_launch(void* const* d_in, const int* in_sizes, int n_in,
                              void* d_out, int out_size, void* d_ws, size_t ws_size,
                              hipStream_t stream) {
    const vf4* S   = (const vf4*)d_in[0];
    const int* L   = (const int*)d_in[1];
    vf4*       out = (vf4*)d_out;

    pad_scatter<<<BLOCKS, THREADS, 0, stream>>>(S, L, out);
}

// Round 2
// 393.589 us; speedup vs baseline: 1.0458x; 1.0458x over previous
//
#include <hip/hip_runtime.h>

// BatchedSequences: scatter concatenated (T,F) fp32 rows into padded
// (B, MAX_SL, F), zero-filling tails. Pure one-pass HBM stream:
// read 203 MB + write 268 MB => ~73 us two-pass HBM floor at 6.4 TB/s.
//
// Fixed shapes (setup_inputs): B=32, F=512, MAX_SL=4096, T=99328.
//
// Measured decomposition (R0/R1 rocprof): timed region = 2 harness
// poison fills (~165 us each, 1 GiB @ ~6.5 TB/s — untouchable) + this
// kernel (~59 us, 471 MB => 8.0 TB/s effective, i.e. partially
// cache-served reads; below the 73 us two-pass HBM floor already).
//
// R1 A/B RESULT (do not "fix" this): swapping the NT loads for regular
// cache-allocating loads cost +26 us on the kernel slice (59 -> 85 us).
// The 1 GiB inter-iteration poison fills flush MALL, so there is no
// cross-iteration S residency to preserve; allocating loads only thrash
// the cache path the store stream transits. NONTEMPORAL ON BOTH SIDES
// is the measured optimum.
//
// Structure: 524288 threads (2048x256) = exactly one batch's worth of
// float4s (4096 rows x 128 v4-cols), so each thread keeps ONE (p, col)
// pair and walks all 32 batches with compile-time-constant strides.
// Loads batched 4-deep ahead of stores (MLP).
//
// Note: HIP float4 is a struct — __builtin_nontemporal_* needs a native
// clang vector type, hence the ext_vector_type alias.

typedef float vf4 __attribute__((ext_vector_type(4)));

constexpr int B_N     = 32;
constexpr int FV      = 128;               // 512 floats = 128 vf4
constexpr int THREADS = 256;
constexpr int BLOCKS  = 2048;
constexpr int NTHREAD = BLOCKS * THREADS;  // 524288 = MAX_SL * FV (one batch)

__global__ __launch_bounds__(THREADS) void pad_scatter(
    const vf4* __restrict__ S,   // (T, FV)
    const int* __restrict__ L,   // (B,)
    vf4*       __restrict__ out) // (B, MAX_SL, FV)
{
    __shared__ int s_len[B_N];
    __shared__ int s_off[B_N];

    if (threadIdx.x < B_N) s_len[threadIdx.x] = L[threadIdx.x];
    __syncthreads();
    if (threadIdx.x < B_N) {
        int acc = 0;
        for (int b = 0; b < (int)threadIdx.x; ++b) acc += s_len[b];
        s_off[threadIdx.x] = acc;
    }
    __syncthreads();

    const int base = blockIdx.x * THREADS + threadIdx.x; // [0, NTHREAD)
    const int col  = base & (FV - 1);
    const int p    = base >> 7;                          // row within batch

    #pragma unroll
    for (int b0 = 0; b0 < B_N; b0 += 4) {
        vf4 v[4];
        // Issue all 4 loads before any store (branches are wave-uniform:
        // all 64 lanes of a wave share the same p).
        #pragma unroll
        for (int j = 0; j < 4; ++j) {
            const int b = b0 + j;
            v[j] = (vf4)(0.f);
            if (p < s_len[b]) {
                v[j] = __builtin_nontemporal_load(
                    &S[(size_t)(s_off[b] + p) * FV + col]);
            }
        }
        #pragma unroll
        for (int j = 0; j < 4; ++j) {
            __builtin_nontemporal_store(
                v[j], &out[(size_t)(b0 + j) * NTHREAD + base]);
        }
    }
}

extern "C" void kernel_launch(void* const* d_in, const int* in_sizes, int n_in,
                              void* d_out, int out_size, void* d_ws, size_t ws_size,
                              hipStream_t stream) {
    const vf4* S   = (const vf4*)d_in[0];
    const int* L   = (const int*)d_in[1];
    vf4*       out = (vf4*)d_out;

    pad_scatter<<<BLOCKS, THREADS, 0, stream>>>(S, L, out);
}